// Round 1
// baseline (351.012 us; speedup 1.0000x reference)
//
#include <hip/hip_runtime.h>
#include <hip/hip_bf16.h>
#include <math.h>

// MHA forward: x[2,2048,1024] fp32 -> out fp32.
// Stage 1: QKV projections (bf16 MFMA, fp32 accum) -> ws (bf16, [b,h,s,dk])
// Stage 2: flash attention per (b,h) -> ctx bf16 [b,s,1024] in ws
// Stage 3: out = ctx @ wo + bo -> d_out fp32
// ws requirement: 4 * 4096*1024 * 2B = 32 MiB.

typedef __attribute__((ext_vector_type(8))) short bf8v;   // 8 bf16 in 4 VGPRs
typedef __attribute__((ext_vector_type(4))) float f32x4;

constexpr int Dm = 1024;
constexpr int NH = 16;
constexpr int DK = 64;
constexpr int BB = 2;
constexpr int SS = 2048;
constexpr int MM = BB * SS;   // 4096

__device__ __forceinline__ unsigned short f2bf(float f) {
  union { float f; unsigned u; } v; v.f = f;
  unsigned r = v.u + 0x7fffu + ((v.u >> 16) & 1u);
  return (unsigned short)(r >> 16);
}

// ---------------- GEMM tile: C[128x128] = A[M,1024] @ W[1024,N] + bias ----------------
// AMODE 0: A fp32; AMODE 1: A bf16 (ushort).
// OMODE 0: store bf16 into head-split [b,h,s,dk] layout; OMODE 1: store fp32 row-major.
template<int AMODE, int OMODE>
__device__ __forceinline__ void gemm_tile(
    const void* __restrict__ Ap, const float* __restrict__ Wp,
    const float* __restrict__ biasp, void* __restrict__ Outp,
    unsigned short* As, unsigned short* Bs)
{
  const int tid  = threadIdx.x;
  const int lane = tid & 63;
  const int wave = tid >> 6;
  const int wm = wave >> 1, wn = wave & 1;
  const int m0 = blockIdx.y * 128, n0 = blockIdx.x * 128;
  const int l15 = lane & 15, l4 = lane >> 4;

  f32x4 acc[4][4] = {};

  for (int k0 = 0; k0 < Dm; k0 += 32) {
    // ---- stage A tile [128 x 32] ----
    if (AMODE == 0) {
      const float* A = (const float*)Ap;
      #pragma unroll
      for (int it = 0; it < 4; ++it) {
        int g = tid + 256 * it;              // 1024 float4s
        int row = g >> 3, kc = (g & 7) << 2;
        float4 v = *(const float4*)(A + (size_t)(m0 + row) * Dm + k0 + kc);
        unsigned short* dst = &As[row * 40 + kc];
        dst[0] = f2bf(v.x); dst[1] = f2bf(v.y); dst[2] = f2bf(v.z); dst[3] = f2bf(v.w);
      }
    } else {
      const unsigned short* A = (const unsigned short*)Ap;
      #pragma unroll
      for (int it = 0; it < 2; ++it) {
        int g = tid + 256 * it;              // 512 ushort8s
        int row = g >> 2, kc = (g & 3) << 3;
        bf8v v = *(const bf8v*)(A + (size_t)(m0 + row) * Dm + k0 + kc);
        *(bf8v*)&As[row * 40 + kc] = v;
      }
    }
    // ---- stage W tile [32 x 128], transposed into Bs[n][k] ----
    #pragma unroll
    for (int it = 0; it < 4; ++it) {
      int g = tid + 256 * it;                // 1024 float4s
      int kr = g >> 5, nc = (g & 31) << 2;
      float4 v = *(const float4*)(Wp + (size_t)(k0 + kr) * Dm + n0 + nc);
      Bs[(nc + 0) * 40 + kr] = f2bf(v.x);
      Bs[(nc + 1) * 40 + kr] = f2bf(v.y);
      Bs[(nc + 2) * 40 + kr] = f2bf(v.z);
      Bs[(nc + 3) * 40 + kr] = f2bf(v.w);
    }
    __syncthreads();

    bf8v af[4], bfr[4];
    #pragma unroll
    for (int i = 0; i < 4; ++i)
      af[i] = *(const bf8v*)&As[(wm * 64 + i * 16 + l15) * 40 + l4 * 8];
    #pragma unroll
    for (int j = 0; j < 4; ++j)
      bfr[j] = *(const bf8v*)&Bs[(wn * 64 + j * 16 + l15) * 40 + l4 * 8];
    #pragma unroll
    for (int i = 0; i < 4; ++i)
      #pragma unroll
      for (int j = 0; j < 4; ++j)
        acc[i][j] = __builtin_amdgcn_mfma_f32_16x16x32_bf16(af[i], bfr[j], acc[i][j], 0, 0, 0);
    __syncthreads();
  }

  // ---- epilogue ----
  #pragma unroll
  for (int i = 0; i < 4; ++i) {
    #pragma unroll
    for (int j = 0; j < 4; ++j) {
      int row = m0 + wm * 64 + i * 16 + l4 * 4;
      int col = n0 + wn * 64 + j * 16 + l15;
      float bias = biasp[col];
      #pragma unroll
      for (int r = 0; r < 4; ++r) {
        float val = acc[i][j][r] + bias;
        int rr = row + r;
        if (OMODE == 0) {
          unsigned short* O = (unsigned short*)Outp;
          int b = rr >> 11, s = rr & 2047, h = col >> 6, d = col & 63;
          O[(((size_t)(b * NH + h) * SS + s) * DK) + d] = f2bf(val);
        } else {
          float* O = (float*)Outp;
          O[(size_t)rr * Dm + col] = val;
        }
      }
    }
  }
}

__global__ __launch_bounds__(256) void proj_kernel(
    const float* __restrict__ x,
    const float* __restrict__ wq, const float* __restrict__ bq,
    const float* __restrict__ wk, const float* __restrict__ bk,
    const float* __restrict__ wv, const float* __restrict__ bv,
    unsigned short* __restrict__ Qh, unsigned short* __restrict__ Kh,
    unsigned short* __restrict__ Vh)
{
  __shared__ unsigned short As[128 * 40];
  __shared__ unsigned short Bs[128 * 40];
  const float* W; const float* bias; unsigned short* Out;
  if (blockIdx.z == 0)      { W = wq; bias = bq; Out = Qh; }
  else if (blockIdx.z == 1) { W = wk; bias = bk; Out = Kh; }
  else                      { W = wv; bias = bv; Out = Vh; }
  gemm_tile<0, 0>(x, W, bias, Out, As, Bs);
}

__global__ __launch_bounds__(256) void outproj_kernel(
    const unsigned short* __restrict__ Ctx, const float* __restrict__ wo,
    const float* __restrict__ bo, float* __restrict__ Out)
{
  __shared__ unsigned short As[128 * 40];
  __shared__ unsigned short Bs[128 * 40];
  gemm_tile<1, 1>(Ctx, wo, bo, Out, As, Bs);
}

// ---------------- Flash attention ----------------
// Grid: (S/128, B*H). Block 256 = 4 waves; wave w owns q rows [q0+w*32, +32).
__global__ __launch_bounds__(256) void attn_kernel(
    const unsigned short* __restrict__ Q, const unsigned short* __restrict__ K,
    const unsigned short* __restrict__ V, unsigned short* __restrict__ Ctx)
{
  __shared__ unsigned short Kl[64 * 72];
  __shared__ unsigned short Vt[64 * 72];     // transposed: Vt[d][key]
  __shared__ unsigned short Pl[4][32 * 72];

  const int tid = threadIdx.x, lane = tid & 63, wave = tid >> 6;
  const int l15 = lane & 15, l4 = lane >> 4;
  const int bh = blockIdx.y;
  const int q0 = blockIdx.x * 128 + wave * 32;
  const size_t base = (size_t)bh * SS * DK;

  const float SCL = 0.125f * 1.44269504088896f;  // scale * log2(e)

  // hoist Q fragments (32 rows x 64 d)
  bf8v qf[2][2];
  #pragma unroll
  for (int i = 0; i < 2; ++i)
    #pragma unroll
    for (int kk = 0; kk < 2; ++kk)
      qf[i][kk] = *(const bf8v*)(Q + base + (size_t)(q0 + i * 16 + l15) * DK + kk * 32 + l4 * 8);

  float mrow[2][4], lrow[2][4];
  f32x4 cacc[2][4] = {};
  #pragma unroll
  for (int i = 0; i < 2; ++i)
    #pragma unroll
    for (int r = 0; r < 4; ++r) { mrow[i][r] = -INFINITY; lrow[i][r] = 0.f; }

  for (int kt = 0; kt < SS; kt += 64) {
    // ---- stage K [64x64] ----
    #pragma unroll
    for (int it = 0; it < 2; ++it) {
      int g = tid + 256 * it;               // 512 ushort8s
      int row = g >> 3, dc = (g & 7) << 3;
      bf8v v = *(const bf8v*)(K + base + (size_t)(kt + row) * DK + dc);
      *(bf8v*)&Kl[row * 72 + dc] = v;
    }
    // ---- stage V transposed ----
    #pragma unroll
    for (int it = 0; it < 2; ++it) {
      int g = tid + 256 * it;
      int row = g >> 3, dc = (g & 7) << 3;
      bf8v v = *(const bf8v*)(V + base + (size_t)(kt + row) * DK + dc);
      #pragma unroll
      for (int q = 0; q < 8; ++q)
        Vt[(dc + q) * 72 + row] = (unsigned short)v[q];
    }
    __syncthreads();

    // ---- scores: S = Q @ K^T ----
    f32x4 sacc[2][4] = {};
    #pragma unroll
    for (int j = 0; j < 4; ++j) {
      #pragma unroll
      for (int kk = 0; kk < 2; ++kk) {
        bf8v kf = *(const bf8v*)&Kl[(j * 16 + l15) * 72 + kk * 32 + l4 * 8];
        #pragma unroll
        for (int i = 0; i < 2; ++i)
          sacc[i][j] = __builtin_amdgcn_mfma_f32_16x16x32_bf16(qf[i][kk], kf, sacc[i][j], 0, 0, 0);
      }
    }

    // ---- online softmax (log2 domain) ----
    #pragma unroll
    for (int i = 0; i < 2; ++i) {
      float mnew[4], alpha[4], lsum[4];
      #pragma unroll
      for (int r = 0; r < 4; ++r) {
        float mx = fmaxf(fmaxf(sacc[i][0][r], sacc[i][1][r]),
                         fmaxf(sacc[i][2][r], sacc[i][3][r])) * SCL;
        mx = fmaxf(mx, __shfl_xor(mx, 1));
        mx = fmaxf(mx, __shfl_xor(mx, 2));
        mx = fmaxf(mx, __shfl_xor(mx, 4));
        mx = fmaxf(mx, __shfl_xor(mx, 8));
        mnew[r] = fmaxf(mrow[i][r], mx);
        lsum[r] = 0.f;
      }
      #pragma unroll
      for (int j = 0; j < 4; ++j)
        #pragma unroll
        for (int r = 0; r < 4; ++r) {
          float p = exp2f(sacc[i][j][r] * SCL - mnew[r]);
          lsum[r] += p;
          Pl[wave][(i * 16 + l4 * 4 + r) * 72 + j * 16 + l15] = f2bf(p);
        }
      #pragma unroll
      for (int r = 0; r < 4; ++r) {
        float ls = lsum[r];
        ls += __shfl_xor(ls, 1); ls += __shfl_xor(ls, 2);
        ls += __shfl_xor(ls, 4); ls += __shfl_xor(ls, 8);
        alpha[r] = exp2f(mrow[i][r] - mnew[r]);
        lrow[i][r] = lrow[i][r] * alpha[r] + ls;
        mrow[i][r] = mnew[r];
      }
      #pragma unroll
      for (int n = 0; n < 4; ++n)
        #pragma unroll
        for (int r = 0; r < 4; ++r)
          cacc[i][n][r] *= alpha[r];
    }

    // ---- PV: ctx += P @ V ----
    #pragma unroll
    for (int kk = 0; kk < 2; ++kk) {
      bf8v pa[2];
      #pragma unroll
      for (int i = 0; i < 2; ++i)
        pa[i] = *(const bf8v*)&Pl[wave][(i * 16 + l15) * 72 + kk * 32 + l4 * 8];
      #pragma unroll
      for (int n = 0; n < 4; ++n) {
        bf8v vb = *(const bf8v*)&Vt[(n * 16 + l15) * 72 + kk * 32 + l4 * 8];
        #pragma unroll
        for (int i = 0; i < 2; ++i)
          cacc[i][n] = __builtin_amdgcn_mfma_f32_16x16x32_bf16(pa[i], vb, cacc[i][n], 0, 0, 0);
      }
    }
    __syncthreads();
  }

  // ---- write ctx (bf16, [b, s, h*64+d]) ----
  const int b = bh >> 4, h = bh & 15;
  #pragma unroll
  for (int i = 0; i < 2; ++i)
    #pragma unroll
    for (int n = 0; n < 4; ++n)
      #pragma unroll
      for (int r = 0; r < 4; ++r) {
        int srow = q0 + i * 16 + l4 * 4 + r;
        int d = h * 64 + n * 16 + l15;
        float val = cacc[i][n][r] / lrow[i][r];
        Ctx[((size_t)(b * SS + srow)) * Dm + d] = f2bf(val);
      }
}

extern "C" void kernel_launch(void* const* d_in, const int* in_sizes, int n_in,
                              void* d_out, int out_size, void* d_ws, size_t ws_size,
                              hipStream_t stream) {
  const float* x  = (const float*)d_in[0];
  const float* wq = (const float*)d_in[1];
  const float* bq = (const float*)d_in[2];
  const float* wk = (const float*)d_in[3];
  const float* bk = (const float*)d_in[4];
  const float* wv = (const float*)d_in[5];
  const float* bv = (const float*)d_in[6];
  const float* wo = (const float*)d_in[7];
  const float* bo = (const float*)d_in[8];
  float* out = (float*)d_out;

  unsigned short* ws  = (unsigned short*)d_ws;
  const size_t PLANE = (size_t)MM * Dm;      // 4096*1024 bf16 elems
  unsigned short* Qh  = ws;
  unsigned short* Kh  = Qh + PLANE;
  unsigned short* Vh  = Kh + PLANE;
  unsigned short* Ctx = Vh + PLANE;

  dim3 blk(256);
  proj_kernel<<<dim3(Dm / 128, MM / 128, 3), blk, 0, stream>>>(
      x, wq, bq, wk, bk, wv, bv, Qh, Kh, Vh);
  attn_kernel<<<dim3(SS / 128, BB * NH), blk, 0, stream>>>(Qh, Kh, Vh, Ctx);
  outproj_kernel<<<dim3(Dm / 128, MM / 128), blk, 0, stream>>>(Ctx, wo, bo, out);
}

// Round 2
// 242.537 us; speedup vs baseline: 1.4472x; 1.4472x over previous
//
#include <hip/hip_runtime.h>
#include <hip/hip_bf16.h>
#include <math.h>

// MHA forward, all-MFMA path.
//  transw(q,k,v) -> proj (x@W, gload_lds B) -> attn (flash, dbuf, swizzled LDS)
//  -> transw(o into freed V plane) -> outproj (both operands gload_lds).
// ws layout (u16 elems), 32 MiB total:
//  Wtqkv [0, 3M) ; Q [4M, 8M) ; K [8M, 12M) ; V [12M, 16M)
//  Ctx   [0, 4M)   (over Wt, after proj done)
//  Wto   [12M, 13M) (over V, after attn done)

typedef __attribute__((ext_vector_type(8))) short bf8v;
typedef __attribute__((ext_vector_type(4))) float f32x4;

constexpr int Dm = 1024;
constexpr int NH = 16;
constexpr int DK = 64;
constexpr int BB = 2;
constexpr int SS = 2048;
constexpr int MM = BB * SS;   // 4096

__device__ __forceinline__ unsigned short f2bf(float f) {
  union { float f; unsigned u; } v; v.f = f;
  unsigned r = v.u + 0x7fffu + ((v.u >> 16) & 1u);
  return (unsigned short)(r >> 16);
}

__device__ __forceinline__ void gl_lds16(const void* g, void* l) {
  __builtin_amdgcn_global_load_lds(
      (const __attribute__((address_space(1))) void*)g,
      (__attribute__((address_space(3))) void*)l, 16, 0, 0);
}

// 4-slot swizzle for 64B-row GEMM tiles: physical slot = s0 ^ swz4(row)
__device__ __forceinline__ int swz4(int r) { return (r ^ (r >> 2)) & 3; }
__device__ __forceinline__ bf8v frag4(const unsigned short* base, int R, int s0) {
  return *(const bf8v*)((const char*)base + R * 64 + ((s0 ^ swz4(R)) << 4));
}
// 8-slot swizzle for 128B-row attn tiles
__device__ __forceinline__ bf8v frag8(const unsigned short* base, int R, int s0) {
  return *(const bf8v*)((const char*)base + R * 128 + (((s0 ^ R) & 7) << 4));
}

// ---------- weight transpose+convert: Wt[o][i] = bf16(W[i][o]) ----------
__global__ __launch_bounds__(256) void transw_kernel(
    const float* __restrict__ w0, const float* __restrict__ w1,
    const float* __restrict__ w2, unsigned short* __restrict__ dstBase)
{
  const float* src = (blockIdx.y == 0) ? w0 : (blockIdx.y == 1) ? w1 : w2;
  unsigned short* dst = dstBase + (size_t)blockIdx.y * (Dm * Dm);
  int idx = blockIdx.x * 256 + threadIdx.x;     // 1024 blocks -> 262144 threads
  int i = idx & (Dm - 1);
  int o = (idx >> 10) << 2;
  float4 v = *(const float4*)(src + (size_t)i * Dm + o);
  dst[(size_t)(o + 0) * Dm + i] = f2bf(v.x);
  dst[(size_t)(o + 1) * Dm + i] = f2bf(v.y);
  dst[(size_t)(o + 2) * Dm + i] = f2bf(v.z);
  dst[(size_t)(o + 3) * Dm + i] = f2bf(v.w);
}

// ---------- QKV projection: C = x @ W + b ; Q/K head-split, V transposed ----------
__global__ __launch_bounds__(256) void proj_kernel(
    const float* __restrict__ x, const unsigned short* __restrict__ WtBase,
    const float* __restrict__ bq, const float* __restrict__ bk, const float* __restrict__ bv,
    unsigned short* __restrict__ Qh, unsigned short* __restrict__ Kh,
    unsigned short* __restrict__ Vh)
{
  __shared__ unsigned short As[128 * 32];
  __shared__ unsigned short Bs[128 * 32];
  const int z = blockIdx.z;
  const unsigned short* W = WtBase + (size_t)z * (Dm * Dm);
  const float* bias = (z == 0) ? bq : (z == 1) ? bk : bv;

  const int tid = threadIdx.x, lane = tid & 63, wave = tid >> 6;
  const int wm = wave >> 1, wn = wave & 1;
  const int m0 = blockIdx.y * 128, n0 = blockIdx.x * 128;
  const int l15 = lane & 15, l4 = lane >> 4;

  f32x4 acc[4][4] = {};

  for (int k0 = 0; k0 < Dm; k0 += 32) {
    // B tile via global_load_lds (linear dest, inverse-swizzled source)
    #pragma unroll
    for (int it = 0; it < 2; ++it) {
      int q = tid + 256 * it;
      int row = q >> 2, sl = q & 3, c = sl ^ swz4(row);
      gl_lds16(W + (size_t)(n0 + row) * Dm + k0 + c * 8,
               (char*)Bs + (size_t)(q - lane) * 16);
    }
    // A tile: fp32 -> bf16 convert, swizzled vector write
    #pragma unroll
    for (int it = 0; it < 2; ++it) {
      int q = tid + 256 * it;
      int row = q >> 2, sl = q & 3, c = sl ^ swz4(row);
      const float* src = x + (size_t)(m0 + row) * Dm + k0 + c * 8;
      float4 a = *(const float4*)src;
      float4 b = *(const float4*)(src + 4);
      bf8v v;
      v[0] = (short)f2bf(a.x); v[1] = (short)f2bf(a.y);
      v[2] = (short)f2bf(a.z); v[3] = (short)f2bf(a.w);
      v[4] = (short)f2bf(b.x); v[5] = (short)f2bf(b.y);
      v[6] = (short)f2bf(b.z); v[7] = (short)f2bf(b.w);
      *(bf8v*)((char*)As + row * 64 + (sl << 4)) = v;
    }
    __syncthreads();

    bf8v af[4], bfr[4];
    #pragma unroll
    for (int i = 0; i < 4; ++i) af[i] = frag4(As, wm * 64 + i * 16 + l15, l4);
    #pragma unroll
    for (int j = 0; j < 4; ++j) bfr[j] = frag4(Bs, wn * 64 + j * 16 + l15, l4);
    #pragma unroll
    for (int i = 0; i < 4; ++i)
      #pragma unroll
      for (int j = 0; j < 4; ++j)
        acc[i][j] = __builtin_amdgcn_mfma_f32_16x16x32_bf16(af[i], bfr[j], acc[i][j], 0, 0, 0);
    __syncthreads();
  }

  unsigned short* Out = (z == 0) ? Qh : (z == 1) ? Kh : Vh;
  #pragma unroll
  for (int i = 0; i < 4; ++i)
    #pragma unroll
    for (int j = 0; j < 4; ++j) {
      int row = m0 + wm * 64 + i * 16 + l4 * 4;
      int col = n0 + wn * 64 + j * 16 + l15;
      float bcol = bias[col];
      int h = col >> 6, d = col & 63;
      #pragma unroll
      for (int r = 0; r < 4; ++r) {
        int rr = row + r;
        int b = rr >> 11, s = rr & 2047;
        unsigned short val = f2bf(acc[i][j][r] + bcol);
        if (z < 2)
          Out[(((size_t)(b * NH + h) * SS + s) * DK) + d] = val;
        else
          Out[((size_t)(b * NH + h) * DK + d) * SS + s] = val;   // V transposed
      }
    }
}

// ---------- output projection: out = Ctx @ wo + bo (fp32) ----------
__global__ __launch_bounds__(256) void outproj_kernel(
    const unsigned short* __restrict__ Ctx, const unsigned short* __restrict__ Wto,
    const float* __restrict__ bo, float* __restrict__ Out)
{
  __shared__ unsigned short As[128 * 32];
  __shared__ unsigned short Bs[128 * 32];
  const int tid = threadIdx.x, lane = tid & 63, wave = tid >> 6;
  const int wm = wave >> 1, wn = wave & 1;
  const int m0 = blockIdx.y * 128, n0 = blockIdx.x * 128;
  const int l15 = lane & 15, l4 = lane >> 4;

  f32x4 acc[4][4] = {};

  for (int k0 = 0; k0 < Dm; k0 += 32) {
    #pragma unroll
    for (int it = 0; it < 2; ++it) {
      int q = tid + 256 * it;
      int row = q >> 2, sl = q & 3, c = sl ^ swz4(row);
      gl_lds16(Ctx + (size_t)(m0 + row) * Dm + k0 + c * 8,
               (char*)As + (size_t)(q - lane) * 16);
      gl_lds16(Wto + (size_t)(n0 + row) * Dm + k0 + c * 8,
               (char*)Bs + (size_t)(q - lane) * 16);
    }
    __syncthreads();

    bf8v af[4], bfr[4];
    #pragma unroll
    for (int i = 0; i < 4; ++i) af[i] = frag4(As, wm * 64 + i * 16 + l15, l4);
    #pragma unroll
    for (int j = 0; j < 4; ++j) bfr[j] = frag4(Bs, wn * 64 + j * 16 + l15, l4);
    #pragma unroll
    for (int i = 0; i < 4; ++i)
      #pragma unroll
      for (int j = 0; j < 4; ++j)
        acc[i][j] = __builtin_amdgcn_mfma_f32_16x16x32_bf16(af[i], bfr[j], acc[i][j], 0, 0, 0);
    __syncthreads();
  }

  #pragma unroll
  for (int i = 0; i < 4; ++i)
    #pragma unroll
    for (int j = 0; j < 4; ++j) {
      int row = m0 + wm * 64 + i * 16 + l4 * 4;
      int col = n0 + wn * 64 + j * 16 + l15;
      float bcol = bo[col];
      #pragma unroll
      for (int r = 0; r < 4; ++r)
        Out[(size_t)(row + r) * Dm + col] = acc[i][j][r] + bcol;
    }
}

// ---------- flash attention ----------
// Grid: (S/128, B*H). 4 waves, wave w owns 32 q rows. K/V double-buffered.
__global__ __launch_bounds__(256) void attn_kernel(
    const unsigned short* __restrict__ Q, const unsigned short* __restrict__ K,
    const unsigned short* __restrict__ Vt, unsigned short* __restrict__ Ctx)
{
  __shared__ unsigned short Kl[2][64 * 64];
  __shared__ unsigned short Vl[2][64 * 64];    // rows = d, cols = keys
  __shared__ unsigned short Pl[4][32 * 76];

  const int tid = threadIdx.x, lane = tid & 63, wave = tid >> 6;
  const int l15 = lane & 15, l4 = lane >> 4;
  const int bh = blockIdx.y;
  const int q0 = blockIdx.x * 128 + wave * 32;
  const size_t base = (size_t)bh * SS * DK;    // Q,K and (transposed) V planes

  const float SCL = 0.125f * 1.44269504088896f;  // 1/sqrt(dk) * log2(e)

  bf8v qf[2][2];
  #pragma unroll
  for (int i = 0; i < 2; ++i)
    #pragma unroll
    for (int kk = 0; kk < 2; ++kk)
      qf[i][kk] = *(const bf8v*)(Q + base + (size_t)(q0 + i * 16 + l15) * DK + kk * 32 + l4 * 8);

  float mrow[2][4], lrow[2][4];
  f32x4 cacc[2][4] = {};
  #pragma unroll
  for (int i = 0; i < 2; ++i)
    #pragma unroll
    for (int r = 0; r < 4; ++r) { mrow[i][r] = -INFINITY; lrow[i][r] = 0.f; }

  auto stage = [&](int bsel, int kt) {
    #pragma unroll
    for (int it = 0; it < 2; ++it) {
      int q = tid + 256 * it;
      int row = q >> 3, sl = q & 7, c = sl ^ (row & 7);
      gl_lds16(K + base + (size_t)(kt + row) * DK + c * 8,
               (char*)Kl[bsel] + (size_t)(q - lane) * 16);
      gl_lds16(Vt + base + (size_t)row * SS + kt + c * 8,
               (char*)Vl[bsel] + (size_t)(q - lane) * 16);
    }
  };

  constexpr int NT = SS / 64;   // 32
  stage(0, 0);
  __syncthreads();
  int cur = 0;

  for (int t = 0; t < NT; ++t) {
    if (t + 1 < NT) stage(cur ^ 1, (t + 1) * 64);
    const unsigned short* Kb = Kl[cur];
    const unsigned short* Vb = Vl[cur];

    // ---- S = Q @ K^T ----
    f32x4 sacc[2][4] = {};
    __builtin_amdgcn_s_setprio(1);
    #pragma unroll
    for (int j = 0; j < 4; ++j)
      #pragma unroll
      for (int kk = 0; kk < 2; ++kk) {
        bf8v kf = frag8(Kb, j * 16 + l15, kk * 4 + l4);
        sacc[0][j] = __builtin_amdgcn_mfma_f32_16x16x32_bf16(qf[0][kk], kf, sacc[0][j], 0, 0, 0);
        sacc[1][j] = __builtin_amdgcn_mfma_f32_16x16x32_bf16(qf[1][kk], kf, sacc[1][j], 0, 0, 0);
      }
    __builtin_amdgcn_s_setprio(0);

    // ---- online softmax with defer-max (THR=8 in log2 domain) ----
    float mnew[2][4];
    bool need = false;
    #pragma unroll
    for (int i = 0; i < 2; ++i)
      #pragma unroll
      for (int r = 0; r < 4; ++r) {
        float mx = fmaxf(fmaxf(sacc[i][0][r], sacc[i][1][r]),
                         fmaxf(sacc[i][2][r], sacc[i][3][r])) * SCL;
        mx = fmaxf(mx, __shfl_xor(mx, 1));
        mx = fmaxf(mx, __shfl_xor(mx, 2));
        mx = fmaxf(mx, __shfl_xor(mx, 4));
        mx = fmaxf(mx, __shfl_xor(mx, 8));
        mnew[i][r] = fmaxf(mrow[i][r], mx);
        need = need || (mnew[i][r] - mrow[i][r] > 8.0f);
      }
    if (__any(need ? 1 : 0)) {
      #pragma unroll
      for (int i = 0; i < 2; ++i)
        #pragma unroll
        for (int r = 0; r < 4; ++r) {
          float alpha = exp2f(mrow[i][r] - mnew[i][r]);
          mrow[i][r] = mnew[i][r];
          lrow[i][r] *= alpha;
          #pragma unroll
          for (int n = 0; n < 4; ++n) cacc[i][n][r] *= alpha;
        }
    }
    #pragma unroll
    for (int i = 0; i < 2; ++i) {
      float lsum[4] = {0.f, 0.f, 0.f, 0.f};
      #pragma unroll
      for (int j = 0; j < 4; ++j)
        #pragma unroll
        for (int r = 0; r < 4; ++r) {
          float p = exp2f(sacc[i][j][r] * SCL - mrow[i][r]);
          lsum[r] += p;
          Pl[wave][(i * 16 + l4 * 4 + r) * 76 + j * 16 + l15] = f2bf(p);
        }
      #pragma unroll
      for (int r = 0; r < 4; ++r) {
        float ls = lsum[r];
        ls += __shfl_xor(ls, 1); ls += __shfl_xor(ls, 2);
        ls += __shfl_xor(ls, 4); ls += __shfl_xor(ls, 8);
        lrow[i][r] += ls;
      }
    }

    // ---- ctx += P @ V ----
    __builtin_amdgcn_s_setprio(1);
    #pragma unroll
    for (int kk = 0; kk < 2; ++kk) {
      bf8v pa[2];
      #pragma unroll
      for (int i = 0; i < 2; ++i)
        pa[i] = *(const bf8v*)&Pl[wave][(i * 16 + l15) * 76 + kk * 32 + l4 * 8];
      #pragma unroll
      for (int n = 0; n < 4; ++n) {
        bf8v vb = frag8(Vb, n * 16 + l15, kk * 4 + l4);
        cacc[0][n] = __builtin_amdgcn_mfma_f32_16x16x32_bf16(pa[0], vb, cacc[0][n], 0, 0, 0);
        cacc[1][n] = __builtin_amdgcn_mfma_f32_16x16x32_bf16(pa[1], vb, cacc[1][n], 0, 0, 0);
      }
    }
    __builtin_amdgcn_s_setprio(0);

    __syncthreads();
    cur ^= 1;
  }

  // ---- write ctx bf16 [b, s, h*64+d] ----
  const int b = bh >> 4, h = bh & 15;
  #pragma unroll
  for (int i = 0; i < 2; ++i)
    #pragma unroll
    for (int n = 0; n < 4; ++n)
      #pragma unroll
      for (int r = 0; r < 4; ++r) {
        int srow = q0 + i * 16 + l4 * 4 + r;
        int d = h * 64 + n * 16 + l15;
        Ctx[(size_t)(b * SS + srow) * Dm + d] = f2bf(cacc[i][n][r] / lrow[i][r]);
      }
}

extern "C" void kernel_launch(void* const* d_in, const int* in_sizes, int n_in,
                              void* d_out, int out_size, void* d_ws, size_t ws_size,
                              hipStream_t stream) {
  const float* x  = (const float*)d_in[0];
  const float* wq = (const float*)d_in[1];
  const float* bq = (const float*)d_in[2];
  const float* wk = (const float*)d_in[3];
  const float* bk = (const float*)d_in[4];
  const float* wv = (const float*)d_in[5];
  const float* bv = (const float*)d_in[6];
  const float* wo = (const float*)d_in[7];
  const float* bo = (const float*)d_in[8];
  float* out = (float*)d_out;

  unsigned short* ws = (unsigned short*)d_ws;
  const size_t PLANE = (size_t)MM * Dm;            // 4 Mi elems = 8 MiB
  unsigned short* Wt  = ws;                        // 3 planes of 1 Mi elems
  unsigned short* Ctx = ws;                        // reuses Wt region after proj
  unsigned short* Qh  = ws + PLANE;
  unsigned short* Kh  = ws + 2 * PLANE;
  unsigned short* Vh  = ws + 3 * PLANE;
  unsigned short* Wto = ws + 3 * PLANE;            // reuses V region after attn

  dim3 blk(256);
  transw_kernel<<<dim3(1024, 3), blk, 0, stream>>>(wq, wk, wv, Wt);
  proj_kernel<<<dim3(Dm / 128, MM / 128, 3), blk, 0, stream>>>(
      x, Wt, bq, bk, bv, Qh, Kh, Vh);
  attn_kernel<<<dim3(SS / 128, BB * NH), blk, 0, stream>>>(Qh, Kh, Vh, Ctx);
  transw_kernel<<<dim3(1024, 1), blk, 0, stream>>>(wo, wo, wo, Wto);
  outproj_kernel<<<dim3(Dm / 128, MM / 128), blk, 0, stream>>>(Ctx, Wto, bo, out);
}

// Round 3
// 199.804 us; speedup vs baseline: 1.7568x; 1.2139x over previous
//
#include <hip/hip_runtime.h>
#include <hip/hip_bf16.h>
#include <math.h>

// MHA forward, all-MFMA path.
//  transw(q,k,v) -> proj (x@W, gload_lds B; Q pre-scaled by 1/8*log2e)
//  -> attn (flash, swapped QK^T, in-lane softmax, packed P^T)
//  -> transw(o) -> outproj.
// ws layout (u16 elems), 32 MiB total:
//  Wtqkv [0, 3M) ; Q [4M, 8M) ; K [8M, 12M) ; V [12M, 16M)
//  Ctx   [0, 4M)   (over Wt, after proj done)
//  Wto   [12M, 13M) (over V, after attn done)

typedef __attribute__((ext_vector_type(8))) short bf8v;
typedef __attribute__((ext_vector_type(4))) float f32x4;

constexpr int Dm = 1024;
constexpr int NH = 16;
constexpr int DK = 64;
constexpr int BB = 2;
constexpr int SS = 2048;
constexpr int MM = BB * SS;   // 4096

__device__ __forceinline__ unsigned short f2bf(float f) {
  union { float f; unsigned u; } v; v.f = f;
  unsigned r = v.u + 0x7fffu + ((v.u >> 16) & 1u);
  return (unsigned short)(r >> 16);
}

__device__ __forceinline__ unsigned cvt_pk_bf16(float lo, float hi) {
  unsigned r;
  asm("v_cvt_pk_bf16_f32 %0, %1, %2" : "=v"(r) : "v"(lo), "v"(hi));
  return r;
}

__device__ __forceinline__ void gl_lds16(const void* g, void* l) {
  __builtin_amdgcn_global_load_lds(
      (const __attribute__((address_space(1))) void*)g,
      (__attribute__((address_space(3))) void*)l, 16, 0, 0);
}

// 4-slot swizzle for 64B-row GEMM tiles: physical slot = s0 ^ swz4(row)
__device__ __forceinline__ int swz4(int r) { return (r ^ (r >> 2)) & 3; }
__device__ __forceinline__ bf8v frag4(const unsigned short* base, int R, int s0) {
  return *(const bf8v*)((const char*)base + R * 64 + ((s0 ^ swz4(R)) << 4));
}
// 8-slot swizzle for 128B-row attn tiles
__device__ __forceinline__ bf8v frag8(const unsigned short* base, int R, int s0) {
  return *(const bf8v*)((const char*)base + R * 128 + (((s0 ^ R) & 7) << 4));
}

// ---------- weight transpose+convert: Wt[o][i] = bf16(W[i][o]) ----------
__global__ __launch_bounds__(256) void transw_kernel(
    const float* __restrict__ w0, const float* __restrict__ w1,
    const float* __restrict__ w2, unsigned short* __restrict__ dstBase)
{
  const float* src = (blockIdx.y == 0) ? w0 : (blockIdx.y == 1) ? w1 : w2;
  unsigned short* dst = dstBase + (size_t)blockIdx.y * (Dm * Dm);
  int idx = blockIdx.x * 256 + threadIdx.x;
  int i = idx & (Dm - 1);
  int o = (idx >> 10) << 2;
  float4 v = *(const float4*)(src + (size_t)i * Dm + o);
  dst[(size_t)(o + 0) * Dm + i] = f2bf(v.x);
  dst[(size_t)(o + 1) * Dm + i] = f2bf(v.y);
  dst[(size_t)(o + 2) * Dm + i] = f2bf(v.z);
  dst[(size_t)(o + 3) * Dm + i] = f2bf(v.w);
}

// ---------- QKV projection: C = x @ W + b ; Q scaled, Q/K head-split, V transposed ----------
__global__ __launch_bounds__(256) void proj_kernel(
    const float* __restrict__ x, const unsigned short* __restrict__ WtBase,
    const float* __restrict__ bq, const float* __restrict__ bk, const float* __restrict__ bv,
    unsigned short* __restrict__ Qh, unsigned short* __restrict__ Kh,
    unsigned short* __restrict__ Vh)
{
  __shared__ unsigned short As[128 * 32];
  __shared__ unsigned short Bs[128 * 32];
  const int z = blockIdx.z;
  const unsigned short* W = WtBase + (size_t)z * (Dm * Dm);
  const float* bias = (z == 0) ? bq : (z == 1) ? bk : bv;

  const int tid = threadIdx.x, lane = tid & 63, wave = tid >> 6;
  const int wm = wave >> 1, wn = wave & 1;
  const int m0 = blockIdx.y * 128, n0 = blockIdx.x * 128;
  const int l15 = lane & 15, l4 = lane >> 4;

  f32x4 acc[4][4] = {};

  for (int k0 = 0; k0 < Dm; k0 += 32) {
    #pragma unroll
    for (int it = 0; it < 2; ++it) {
      int q = tid + 256 * it;
      int row = q >> 2, sl = q & 3, c = sl ^ swz4(row);
      gl_lds16(W + (size_t)(n0 + row) * Dm + k0 + c * 8,
               (char*)Bs + (size_t)(q - lane) * 16);
    }
    #pragma unroll
    for (int it = 0; it < 2; ++it) {
      int q = tid + 256 * it;
      int row = q >> 2, sl = q & 3, c = sl ^ swz4(row);
      const float* src = x + (size_t)(m0 + row) * Dm + k0 + c * 8;
      float4 a = *(const float4*)src;
      float4 b = *(const float4*)(src + 4);
      bf8v v;
      v[0] = (short)f2bf(a.x); v[1] = (short)f2bf(a.y);
      v[2] = (short)f2bf(a.z); v[3] = (short)f2bf(a.w);
      v[4] = (short)f2bf(b.x); v[5] = (short)f2bf(b.y);
      v[6] = (short)f2bf(b.z); v[7] = (short)f2bf(b.w);
      *(bf8v*)((char*)As + row * 64 + (sl << 4)) = v;
    }
    __syncthreads();

    bf8v af[4], bfr[4];
    #pragma unroll
    for (int i = 0; i < 4; ++i) af[i] = frag4(As, wm * 64 + i * 16 + l15, l4);
    #pragma unroll
    for (int j = 0; j < 4; ++j) bfr[j] = frag4(Bs, wn * 64 + j * 16 + l15, l4);
    #pragma unroll
    for (int i = 0; i < 4; ++i)
      #pragma unroll
      for (int j = 0; j < 4; ++j)
        acc[i][j] = __builtin_amdgcn_mfma_f32_16x16x32_bf16(af[i], bfr[j], acc[i][j], 0, 0, 0);
    __syncthreads();
  }

  unsigned short* Out = (z == 0) ? Qh : (z == 1) ? Kh : Vh;
  const float oscale = (z == 0) ? 0.18033688011112042f : 1.0f;  // 1/8 * log2(e)
  #pragma unroll
  for (int i = 0; i < 4; ++i)
    #pragma unroll
    for (int j = 0; j < 4; ++j) {
      int row = m0 + wm * 64 + i * 16 + l4 * 4;
      int col = n0 + wn * 64 + j * 16 + l15;
      float bcol = bias[col];
      int h = col >> 6, d = col & 63;
      #pragma unroll
      for (int r = 0; r < 4; ++r) {
        int rr = row + r;
        int b = rr >> 11, s = rr & 2047;
        unsigned short val = f2bf((acc[i][j][r] + bcol) * oscale);
        if (z < 2)
          Out[(((size_t)(b * NH + h) * SS + s) * DK) + d] = val;
        else
          Out[((size_t)(b * NH + h) * DK + d) * SS + s] = val;   // V transposed
      }
    }
}

// ---------- output projection: out = Ctx @ wo + bo (fp32) ----------
__global__ __launch_bounds__(256) void outproj_kernel(
    const unsigned short* __restrict__ Ctx, const unsigned short* __restrict__ Wto,
    const float* __restrict__ bo, float* __restrict__ Out)
{
  __shared__ unsigned short As[128 * 32];
  __shared__ unsigned short Bs[128 * 32];
  const int tid = threadIdx.x, lane = tid & 63, wave = tid >> 6;
  const int wm = wave >> 1, wn = wave & 1;
  const int m0 = blockIdx.y * 128, n0 = blockIdx.x * 128;
  const int l15 = lane & 15, l4 = lane >> 4;

  f32x4 acc[4][4] = {};

  for (int k0 = 0; k0 < Dm; k0 += 32) {
    #pragma unroll
    for (int it = 0; it < 2; ++it) {
      int q = tid + 256 * it;
      int row = q >> 2, sl = q & 3, c = sl ^ swz4(row);
      gl_lds16(Ctx + (size_t)(m0 + row) * Dm + k0 + c * 8,
               (char*)As + (size_t)(q - lane) * 16);
      gl_lds16(Wto + (size_t)(n0 + row) * Dm + k0 + c * 8,
               (char*)Bs + (size_t)(q - lane) * 16);
    }
    __syncthreads();

    bf8v af[4], bfr[4];
    #pragma unroll
    for (int i = 0; i < 4; ++i) af[i] = frag4(As, wm * 64 + i * 16 + l15, l4);
    #pragma unroll
    for (int j = 0; j < 4; ++j) bfr[j] = frag4(Bs, wn * 64 + j * 16 + l15, l4);
    #pragma unroll
    for (int i = 0; i < 4; ++i)
      #pragma unroll
      for (int j = 0; j < 4; ++j)
        acc[i][j] = __builtin_amdgcn_mfma_f32_16x16x32_bf16(af[i], bfr[j], acc[i][j], 0, 0, 0);
    __syncthreads();
  }

  #pragma unroll
  for (int i = 0; i < 4; ++i)
    #pragma unroll
    for (int j = 0; j < 4; ++j) {
      int row = m0 + wm * 64 + i * 16 + l4 * 4;
      int col = n0 + wn * 64 + j * 16 + l15;
      float bcol = bo[col];
      #pragma unroll
      for (int r = 0; r < 4; ++r)
        Out[(size_t)(row + r) * Dm + col] = acc[i][j][r] + bcol;
    }
}

// ---------- flash attention (swapped QK^T, in-lane softmax) ----------
// Grid: (S/128, B*H). 4 waves, wave w owns 32 q rows. K/V double-buffered.
constexpr int PSTR = 88;  // P^T row stride (elems); 176B = 16B-aligned, 2-way banks

__global__ __launch_bounds__(256) void attn_kernel(
    const unsigned short* __restrict__ Q, const unsigned short* __restrict__ K,
    const unsigned short* __restrict__ Vt, unsigned short* __restrict__ Ctx)
{
  __shared__ unsigned short Kl[2][64 * 64];
  __shared__ unsigned short Vl[2][64 * 64];    // rows = d, cols = keys
  __shared__ unsigned short Pt[4][32 * PSTR];  // per-wave P^T as [q][k]

  const int tid = threadIdx.x, lane = tid & 63, wave = tid >> 6;
  const int l15 = lane & 15, g = lane >> 4;
  const int bh = blockIdx.y;
  const int q0 = blockIdx.x * 128 + wave * 32;
  const size_t base = (size_t)bh * SS * DK;

  // Q fragments (pre-scaled by 1/8*log2e in proj)
  bf8v qf[2][2];
  #pragma unroll
  for (int i = 0; i < 2; ++i)
    #pragma unroll
    for (int kk = 0; kk < 2; ++kk)
      qf[i][kk] = *(const bf8v*)(Q + base + (size_t)(q0 + i * 16 + l15) * DK + kk * 32 + g * 8);

  float m = -INFINITY;
  float lpart[2] = {0.f, 0.f};
  f32x4 cacc[2][4] = {};     // ctx^T fragments: [q-tile i][d-tile n]

  auto stage = [&](int bsel, int kt) {
    #pragma unroll
    for (int it = 0; it < 2; ++it) {
      int q = tid + 256 * it;
      int row = q >> 3, sl = q & 7, c = sl ^ (row & 7);
      gl_lds16(K + base + (size_t)(kt + row) * DK + c * 8,
               (char*)Kl[bsel] + (size_t)(q - lane) * 16);
      gl_lds16(Vt + base + (size_t)row * SS + kt + c * 8,
               (char*)Vl[bsel] + (size_t)(q - lane) * 16);
    }
  };

  constexpr int NT = SS / 64;   // 32
  stage(0, 0);
  __syncthreads();
  int cur = 0;

  for (int t = 0; t < NT; ++t) {
    if (t + 1 < NT) stage(cur ^ 1, (t + 1) * 64);
    const unsigned short* Kb = Kl[cur];
    const unsigned short* Vb = Vl[cur];

    // ---- S^T = K @ Q' : st[i][j] tile has rows=k_local, cols=q_local ----
    f32x4 st[2][4] = {};
    __builtin_amdgcn_s_setprio(1);
    #pragma unroll
    for (int j = 0; j < 4; ++j)
      #pragma unroll
      for (int kk = 0; kk < 2; ++kk) {
        bf8v kf = frag8(Kb, j * 16 + l15, kk * 4 + g);
        st[0][j] = __builtin_amdgcn_mfma_f32_16x16x32_bf16(kf, qf[0][kk], st[0][j], 0, 0, 0);
        st[1][j] = __builtin_amdgcn_mfma_f32_16x16x32_bf16(kf, qf[1][kk], st[1][j], 0, 0, 0);
      }
    __builtin_amdgcn_s_setprio(0);

    // ---- wave-global max (exact softmax: shared numerator/denominator scale) ----
    float mx = st[0][0][0];
    #pragma unroll
    for (int i = 0; i < 2; ++i)
      #pragma unroll
      for (int j = 0; j < 4; ++j)
        #pragma unroll
        for (int r = 0; r < 4; ++r) mx = fmaxf(mx, st[i][j][r]);
    mx = fmaxf(mx, __shfl_xor(mx, 1));
    mx = fmaxf(mx, __shfl_xor(mx, 2));
    mx = fmaxf(mx, __shfl_xor(mx, 4));
    mx = fmaxf(mx, __shfl_xor(mx, 8));
    mx = fmaxf(mx, __shfl_xor(mx, 16));
    mx = fmaxf(mx, __shfl_xor(mx, 32));

    // defer-max (THR=8): wave-uniform
    if (mx - m > 8.0f) {
      float mnew = mx;
      float alpha = exp2f(m - mnew);   // first tile: exp2(-inf)=0
      m = mnew;
      lpart[0] *= alpha; lpart[1] *= alpha;
      #pragma unroll
      for (int i = 0; i < 2; ++i)
        #pragma unroll
        for (int n = 0; n < 4; ++n)
          #pragma unroll
          for (int r = 0; r < 4; ++r) cacc[i][n][r] *= alpha;
    }

    // ---- P = exp2(S^T - m), pack to bf16, store P^T[q][k] ----
    #pragma unroll
    for (int i = 0; i < 2; ++i) {
      unsigned short* prow = &Pt[wave][(i * 16 + l15) * PSTR];
      #pragma unroll
      for (int j = 0; j < 4; ++j) {
        float p0 = exp2f(st[i][j][0] - m);
        float p1 = exp2f(st[i][j][1] - m);
        float p2 = exp2f(st[i][j][2] - m);
        float p3 = exp2f(st[i][j][3] - m);
        lpart[i] += (p0 + p1) + (p2 + p3);
        *(unsigned*)(prow + j * 16 + 4 * g)     = cvt_pk_bf16(p0, p1);
        *(unsigned*)(prow + j * 16 + 4 * g + 2) = cvt_pk_bf16(p2, p3);
      }
    }

    // ---- ctx^T += V^T @ P^T ----
    __builtin_amdgcn_s_setprio(1);
    #pragma unroll
    for (int kk = 0; kk < 2; ++kk) {
      bf8v pb[2];
      #pragma unroll
      for (int i = 0; i < 2; ++i)
        pb[i] = *(const bf8v*)&Pt[wave][(i * 16 + l15) * PSTR + kk * 32 + 8 * g];
      #pragma unroll
      for (int n = 0; n < 4; ++n) {
        bf8v vb = frag8(Vb, n * 16 + l15, kk * 4 + g);
        cacc[0][n] = __builtin_amdgcn_mfma_f32_16x16x32_bf16(vb, pb[0], cacc[0][n], 0, 0, 0);
        cacc[1][n] = __builtin_amdgcn_mfma_f32_16x16x32_bf16(vb, pb[1], cacc[1][n], 0, 0, 0);
      }
    }
    __builtin_amdgcn_s_setprio(0);

    __syncthreads();
    cur ^= 1;
  }

  // ---- finalize: cross-group l reduce, normalize, pack 4 d-values / store 8B ----
  const int b = bh >> 4, h = bh & 15;
  #pragma unroll
  for (int i = 0; i < 2; ++i) {
    float lf = lpart[i];
    lf += __shfl_xor(lf, 16);
    lf += __shfl_xor(lf, 32);
    float inv = 1.0f / lf;
    int s = q0 + i * 16 + l15;
    #pragma unroll
    for (int n = 0; n < 4; ++n) {
      uint2 w;
      w.x = cvt_pk_bf16(cacc[i][n][0] * inv, cacc[i][n][1] * inv);
      w.y = cvt_pk_bf16(cacc[i][n][2] * inv, cacc[i][n][3] * inv);
      int d = h * 64 + n * 16 + g * 4;
      *(uint2*)(Ctx + (size_t)(b * SS + s) * Dm + d) = w;
    }
  }
}

extern "C" void kernel_launch(void* const* d_in, const int* in_sizes, int n_in,
                              void* d_out, int out_size, void* d_ws, size_t ws_size,
                              hipStream_t stream) {
  const float* x  = (const float*)d_in[0];
  const float* wq = (const float*)d_in[1];
  const float* bq = (const float*)d_in[2];
  const float* wk = (const float*)d_in[3];
  const float* bk = (const float*)d_in[4];
  const float* wv = (const float*)d_in[5];
  const float* bv = (const float*)d_in[6];
  const float* wo = (const float*)d_in[7];
  const float* bo = (const float*)d_in[8];
  float* out = (float*)d_out;

  unsigned short* ws = (unsigned short*)d_ws;
  const size_t PLANE = (size_t)MM * Dm;            // 4 Mi elems = 8 MiB
  unsigned short* Wt  = ws;                        // 3 planes of 1 Mi elems
  unsigned short* Ctx = ws;                        // reuses Wt region after proj
  unsigned short* Qh  = ws + PLANE;
  unsigned short* Kh  = ws + 2 * PLANE;
  unsigned short* Vh  = ws + 3 * PLANE;
  unsigned short* Wto = ws + 3 * PLANE;            // reuses V region after attn

  dim3 blk(256);
  transw_kernel<<<dim3(1024, 3), blk, 0, stream>>>(wq, wk, wv, Wt);
  proj_kernel<<<dim3(Dm / 128, MM / 128, 3), blk, 0, stream>>>(
      x, Wt, bq, bk, bv, Qh, Kh, Vh);
  attn_kernel<<<dim3(SS / 128, BB * NH), blk, 0, stream>>>(Qh, Kh, Vh, Ctx);
  transw_kernel<<<dim3(1024, 1), blk, 0, stream>>>(wo, wo, wo, Wto);
  outproj_kernel<<<dim3(Dm / 128, MM / 128), blk, 0, stream>>>(Ctx, Wto, bo, out);
}

// Round 4
// 157.908 us; speedup vs baseline: 2.2229x; 1.2653x over previous
//
#include <hip/hip_runtime.h>
#include <hip/hip_bf16.h>
#include <math.h>

// MHA forward, all-MFMA path.
//  transw(q,k,v,o) -> proj (x@W, dbuf 2-phase; Q pre-scaled by 1/8*log2e)
//  -> attn (flash, swapped QK^T, in-lane softmax; ctx written head-split
//     over the Q plane) -> outproj (dbuf 2-phase, head-split A reads).
// ws layout (u16 elems), 32 MiB total:
//  Wt q,k,v,o [0,4M) ; Q [4M,8M) ; K [8M,12M) ; V [12M,16M)
//  Ctx = Q plane (head-split [b,h,s,d]), written by attn after Q-frag hoist.

typedef __attribute__((ext_vector_type(8))) short bf8v;
typedef __attribute__((ext_vector_type(4))) float f32x4;

constexpr int Dm = 1024;
constexpr int NH = 16;
constexpr int DK = 64;
constexpr int BB = 2;
constexpr int SS = 2048;
constexpr int MM = BB * SS;   // 4096

__device__ __forceinline__ unsigned short f2bf(float f) {
  union { float f; unsigned u; } v; v.f = f;
  unsigned r = v.u + 0x7fffu + ((v.u >> 16) & 1u);
  return (unsigned short)(r >> 16);
}

__device__ __forceinline__ unsigned cvt_pk_bf16(float lo, float hi) {
  unsigned r;
  asm("v_cvt_pk_bf16_f32 %0, %1, %2" : "=v"(r) : "v"(lo), "v"(hi));
  return r;
}

__device__ __forceinline__ void gl_lds16(const void* g, void* l) {
  __builtin_amdgcn_global_load_lds(
      (const __attribute__((address_space(1))) void*)g,
      (__attribute__((address_space(3))) void*)l, 16, 0, 0);
}

// 4-slot swizzle for 64B-row GEMM tiles: physical slot = s0 ^ swz4(row)
__device__ __forceinline__ int swz4(int r) { return (r ^ (r >> 2)) & 3; }
__device__ __forceinline__ bf8v frag4(const unsigned short* base, int R, int s0) {
  return *(const bf8v*)((const char*)base + R * 64 + ((s0 ^ swz4(R)) << 4));
}
// 8-slot swizzle for 128B-row attn tiles
__device__ __forceinline__ bf8v frag8(const unsigned short* base, int R, int s0) {
  return *(const bf8v*)((const char*)base + R * 128 + (((s0 ^ R) & 7) << 4));
}

// ---------- weight transpose+convert: Wt[o][i] = bf16(W[i][o]) ----------
__global__ __launch_bounds__(256) void transw_kernel(
    const float* __restrict__ w0, const float* __restrict__ w1,
    const float* __restrict__ w2, const float* __restrict__ w3,
    unsigned short* __restrict__ dstBase)
{
  const float* src = (blockIdx.y == 0) ? w0 : (blockIdx.y == 1) ? w1
                   : (blockIdx.y == 2) ? w2 : w3;
  unsigned short* dst = dstBase + (size_t)blockIdx.y * (Dm * Dm);
  int idx = blockIdx.x * 256 + threadIdx.x;
  int i = idx & (Dm - 1);
  int o = (idx >> 10) << 2;
  float4 v = *(const float4*)(src + (size_t)i * Dm + o);
  dst[(size_t)(o + 0) * Dm + i] = f2bf(v.x);
  dst[(size_t)(o + 1) * Dm + i] = f2bf(v.y);
  dst[(size_t)(o + 2) * Dm + i] = f2bf(v.z);
  dst[(size_t)(o + 3) * Dm + i] = f2bf(v.w);
}

// ---------- QKV projection: C = x @ W + b ; Q scaled, Q/K head-split, V transposed ----------
__global__ __launch_bounds__(256) void proj_kernel(
    const float* __restrict__ x, const unsigned short* __restrict__ WtBase,
    const float* __restrict__ bq, const float* __restrict__ bk, const float* __restrict__ bv,
    unsigned short* __restrict__ Qh, unsigned short* __restrict__ Kh,
    unsigned short* __restrict__ Vh)
{
  __shared__ unsigned short As[2][128 * 32];
  __shared__ unsigned short Bs[2][128 * 32];
  const int z = blockIdx.z;
  const unsigned short* W = WtBase + (size_t)z * (Dm * Dm);
  const float* bias = (z == 0) ? bq : (z == 1) ? bk : bv;

  const int tid = threadIdx.x, lane = tid & 63, wave = tid >> 6;
  const int wm = wave >> 1, wn = wave & 1;
  const int m0 = blockIdx.y * 128, n0 = blockIdx.x * 128;
  const int l15 = lane & 15, l4 = lane >> 4;

  // staging geometry (two 16B chunks per thread per tile)
  const int q1 = tid, q2 = tid + 256;
  const int rw1 = q1 >> 2, sl1 = q1 & 3, c1 = sl1 ^ swz4(rw1);
  const int rw2 = q2 >> 2, sl2 = q2 & 3, c2 = sl2 ^ swz4(rw2);
  const int ldsOff1 = (q1 - lane) * 16, ldsOff2 = (q2 - lane) * 16;

  f32x4 acc[4][4] = {};
  float4 a1, a1b, a2, a2b;

  auto loadA = [&](int k0) {
    const float* s1 = x + (size_t)(m0 + rw1) * Dm + k0 + c1 * 8;
    const float* s2 = x + (size_t)(m0 + rw2) * Dm + k0 + c2 * 8;
    a1 = *(const float4*)s1; a1b = *(const float4*)(s1 + 4);
    a2 = *(const float4*)s2; a2b = *(const float4*)(s2 + 4);
  };
  auto stageB = [&](int buf, int k0) {
    gl_lds16(W + (size_t)(n0 + rw1) * Dm + k0 + c1 * 8, (char*)Bs[buf] + ldsOff1);
    gl_lds16(W + (size_t)(n0 + rw2) * Dm + k0 + c2 * 8, (char*)Bs[buf] + ldsOff2);
  };
  auto writeA = [&](int buf) {
    bf8v v;
    v[0] = (short)f2bf(a1.x);  v[1] = (short)f2bf(a1.y);
    v[2] = (short)f2bf(a1.z);  v[3] = (short)f2bf(a1.w);
    v[4] = (short)f2bf(a1b.x); v[5] = (short)f2bf(a1b.y);
    v[6] = (short)f2bf(a1b.z); v[7] = (short)f2bf(a1b.w);
    *(bf8v*)((char*)As[buf] + rw1 * 64 + (sl1 << 4)) = v;
    v[0] = (short)f2bf(a2.x);  v[1] = (short)f2bf(a2.y);
    v[2] = (short)f2bf(a2.z);  v[3] = (short)f2bf(a2.w);
    v[4] = (short)f2bf(a2b.x); v[5] = (short)f2bf(a2b.y);
    v[6] = (short)f2bf(a2b.z); v[7] = (short)f2bf(a2b.w);
    *(bf8v*)((char*)As[buf] + rw2 * 64 + (sl2 << 4)) = v;
  };

  // prologue
  loadA(0);
  stageB(0, 0);
  writeA(0);
  __syncthreads();

  for (int k0 = 0; k0 < Dm; k0 += 32) {
    const int cur = (k0 >> 5) & 1, nxt = cur ^ 1;
    const bool more = (k0 + 32) < Dm;
    if (more) { loadA(k0 + 32); stageB(nxt, k0 + 32); }

    bf8v af[4], bfr[4];
    #pragma unroll
    for (int i = 0; i < 4; ++i) af[i] = frag4(As[cur], wm * 64 + i * 16 + l15, l4);
    #pragma unroll
    for (int j = 0; j < 4; ++j) bfr[j] = frag4(Bs[cur], wn * 64 + j * 16 + l15, l4);
    __builtin_amdgcn_s_setprio(1);
    #pragma unroll
    for (int i = 0; i < 4; ++i)
      #pragma unroll
      for (int j = 0; j < 4; ++j)
        acc[i][j] = __builtin_amdgcn_mfma_f32_16x16x32_bf16(af[i], bfr[j], acc[i][j], 0, 0, 0);
    __builtin_amdgcn_s_setprio(0);

    if (more) writeA(nxt);
    __syncthreads();
  }

  unsigned short* Out = (z == 0) ? Qh : (z == 1) ? Kh : Vh;
  const float oscale = (z == 0) ? 0.18033688011112042f : 1.0f;  // 1/8 * log2(e)
  #pragma unroll
  for (int i = 0; i < 4; ++i)
    #pragma unroll
    for (int j = 0; j < 4; ++j) {
      int row = m0 + wm * 64 + i * 16 + l4 * 4;
      int col = n0 + wn * 64 + j * 16 + l15;
      float bcol = bias[col];
      int h = col >> 6, d = col & 63;
      #pragma unroll
      for (int r = 0; r < 4; ++r) {
        int rr = row + r;
        int b = rr >> 11, s = rr & 2047;
        unsigned short val = f2bf((acc[i][j][r] + bcol) * oscale);
        if (z < 2)
          Out[(((size_t)(b * NH + h) * SS + s) * DK) + d] = val;
        else
          Out[((size_t)(b * NH + h) * DK + d) * SS + s] = val;   // V transposed
      }
    }
}

// ---------- output projection: out = Ctx @ wo + bo (fp32) ----------
// Ctx is head-split bf16 [b,h,s,d] (the overwritten Q plane).
__global__ __launch_bounds__(256) void outproj_kernel(
    const unsigned short* __restrict__ Ctx, const unsigned short* __restrict__ Wto,
    const float* __restrict__ bo, float* __restrict__ Out)
{
  __shared__ unsigned short As[2][128 * 32];
  __shared__ unsigned short Bs[2][128 * 32];
  const int tid = threadIdx.x, lane = tid & 63, wave = tid >> 6;
  const int wm = wave >> 1, wn = wave & 1;
  const int m0 = blockIdx.y * 128, n0 = blockIdx.x * 128;
  const int l15 = lane & 15, l4 = lane >> 4;

  const int q1 = tid, q2 = tid + 256;
  const int rw1 = q1 >> 2, sl1 = q1 & 3, c1 = sl1 ^ swz4(rw1);
  const int rw2 = q2 >> 2, sl2 = q2 & 3, c2 = sl2 ^ swz4(rw2);
  const int ldsOff1 = (q1 - lane) * 16, ldsOff2 = (q2 - lane) * 16;

  // head-split A source addresses (b,h constant per chunk)
  auto srcA = [&](int rw, int c, int k0) -> const unsigned short* {
    int rr = m0 + rw, b = rr >> 11, s = rr & 2047;
    int col = k0 + c * 8, h = col >> 6, d = col & 63;
    return Ctx + ((size_t)(b * NH + h) * SS + s) * DK + d;
  };
  auto stageAB = [&](int buf, int k0) {
    gl_lds16(srcA(rw1, c1, k0), (char*)As[buf] + ldsOff1);
    gl_lds16(srcA(rw2, c2, k0), (char*)As[buf] + ldsOff2);
    gl_lds16(Wto + (size_t)(n0 + rw1) * Dm + k0 + c1 * 8, (char*)Bs[buf] + ldsOff1);
    gl_lds16(Wto + (size_t)(n0 + rw2) * Dm + k0 + c2 * 8, (char*)Bs[buf] + ldsOff2);
  };

  f32x4 acc[4][4] = {};

  stageAB(0, 0);
  __syncthreads();

  for (int k0 = 0; k0 < Dm; k0 += 32) {
    const int cur = (k0 >> 5) & 1, nxt = cur ^ 1;
    if (k0 + 32 < Dm) stageAB(nxt, k0 + 32);

    bf8v af[4], bfr[4];
    #pragma unroll
    for (int i = 0; i < 4; ++i) af[i] = frag4(As[cur], wm * 64 + i * 16 + l15, l4);
    #pragma unroll
    for (int j = 0; j < 4; ++j) bfr[j] = frag4(Bs[cur], wn * 64 + j * 16 + l15, l4);
    __builtin_amdgcn_s_setprio(1);
    #pragma unroll
    for (int i = 0; i < 4; ++i)
      #pragma unroll
      for (int j = 0; j < 4; ++j)
        acc[i][j] = __builtin_amdgcn_mfma_f32_16x16x32_bf16(af[i], bfr[j], acc[i][j], 0, 0, 0);
    __builtin_amdgcn_s_setprio(0);
    __syncthreads();
  }

  #pragma unroll
  for (int i = 0; i < 4; ++i)
    #pragma unroll
    for (int j = 0; j < 4; ++j) {
      int row = m0 + wm * 64 + i * 16 + l4 * 4;
      int col = n0 + wn * 64 + j * 16 + l15;
      float bcol = bo[col];
      #pragma unroll
      for (int r = 0; r < 4; ++r)
        Out[(size_t)(row + r) * Dm + col] = acc[i][j][r] + bcol;
    }
}

// ---------- flash attention (swapped QK^T, in-lane softmax) ----------
// Grid: (S/128, B*H). 4 waves, wave w owns 32 q rows. K/V double-buffered.
// Ctx is written head-split INTO the Q plane (each wave overwrites exactly
// the Q rows it hoisted into registers at kernel start).
constexpr int PSTR = 88;  // P^T row stride (elems)

__global__ __launch_bounds__(256) void attn_kernel(
    const unsigned short* __restrict__ Q, const unsigned short* __restrict__ K,
    const unsigned short* __restrict__ Vt, unsigned short* __restrict__ CtxQ)
{
  __shared__ unsigned short Kl[2][64 * 64];
  __shared__ unsigned short Vl[2][64 * 64];    // rows = d, cols = keys
  __shared__ unsigned short Pt[4][32 * PSTR];  // per-wave P^T as [q][k]

  const int tid = threadIdx.x, lane = tid & 63, wave = tid >> 6;
  const int l15 = lane & 15, g = lane >> 4;
  const int bh = blockIdx.y;
  const int q0 = blockIdx.x * 128 + wave * 32;
  const size_t base = (size_t)bh * SS * DK;

  // Q fragments (pre-scaled by 1/8*log2e in proj)
  bf8v qf[2][2];
  #pragma unroll
  for (int i = 0; i < 2; ++i)
    #pragma unroll
    for (int kk = 0; kk < 2; ++kk)
      qf[i][kk] = *(const bf8v*)(Q + base + (size_t)(q0 + i * 16 + l15) * DK + kk * 32 + g * 8);

  float m = -INFINITY;
  float lpart[2] = {0.f, 0.f};
  f32x4 cacc[2][4] = {};     // ctx^T fragments: [q-tile i][d-tile n]

  auto stage = [&](int bsel, int kt) {
    #pragma unroll
    for (int it = 0; it < 2; ++it) {
      int q = tid + 256 * it;
      int row = q >> 3, sl = q & 7, c = sl ^ (row & 7);
      gl_lds16(K + base + (size_t)(kt + row) * DK + c * 8,
               (char*)Kl[bsel] + (size_t)(q - lane) * 16);
      gl_lds16(Vt + base + (size_t)row * SS + kt + c * 8,
               (char*)Vl[bsel] + (size_t)(q - lane) * 16);
    }
  };

  constexpr int NT = SS / 64;   // 32
  stage(0, 0);
  __syncthreads();
  int cur = 0;

  for (int t = 0; t < NT; ++t) {
    if (t + 1 < NT) stage(cur ^ 1, (t + 1) * 64);
    const unsigned short* Kb = Kl[cur];
    const unsigned short* Vb = Vl[cur];

    // ---- S^T = K @ Q' ----
    f32x4 st[2][4] = {};
    __builtin_amdgcn_s_setprio(1);
    #pragma unroll
    for (int j = 0; j < 4; ++j)
      #pragma unroll
      for (int kk = 0; kk < 2; ++kk) {
        bf8v kf = frag8(Kb, j * 16 + l15, kk * 4 + g);
        st[0][j] = __builtin_amdgcn_mfma_f32_16x16x32_bf16(kf, qf[0][kk], st[0][j], 0, 0, 0);
        st[1][j] = __builtin_amdgcn_mfma_f32_16x16x32_bf16(kf, qf[1][kk], st[1][j], 0, 0, 0);
      }
    __builtin_amdgcn_s_setprio(0);

    // ---- wave-global max ----
    float mx = st[0][0][0];
    #pragma unroll
    for (int i = 0; i < 2; ++i)
      #pragma unroll
      for (int j = 0; j < 4; ++j)
        #pragma unroll
        for (int r = 0; r < 4; ++r) mx = fmaxf(mx, st[i][j][r]);
    mx = fmaxf(mx, __shfl_xor(mx, 1));
    mx = fmaxf(mx, __shfl_xor(mx, 2));
    mx = fmaxf(mx, __shfl_xor(mx, 4));
    mx = fmaxf(mx, __shfl_xor(mx, 8));
    mx = fmaxf(mx, __shfl_xor(mx, 16));
    mx = fmaxf(mx, __shfl_xor(mx, 32));

    // defer-max (THR=8), wave-uniform
    if (mx - m > 8.0f) {
      float mnew = mx;
      float alpha = exp2f(m - mnew);
      m = mnew;
      lpart[0] *= alpha; lpart[1] *= alpha;
      #pragma unroll
      for (int i = 0; i < 2; ++i)
        #pragma unroll
        for (int n = 0; n < 4; ++n)
          #pragma unroll
          for (int r = 0; r < 4; ++r) cacc[i][n][r] *= alpha;
    }

    // ---- P = exp2(S^T - m), pack, store P^T[q][k] ----
    #pragma unroll
    for (int i = 0; i < 2; ++i) {
      unsigned short* prow = &Pt[wave][(i * 16 + l15) * PSTR];
      #pragma unroll
      for (int j = 0; j < 4; ++j) {
        float p0 = exp2f(st[i][j][0] - m);
        float p1 = exp2f(st[i][j][1] - m);
        float p2 = exp2f(st[i][j][2] - m);
        float p3 = exp2f(st[i][j][3] - m);
        lpart[i] += (p0 + p1) + (p2 + p3);
        *(unsigned*)(prow + j * 16 + 4 * g)     = cvt_pk_bf16(p0, p1);
        *(unsigned*)(prow + j * 16 + 4 * g + 2) = cvt_pk_bf16(p2, p3);
      }
    }

    // ---- ctx^T += V^T @ P^T ----
    __builtin_amdgcn_s_setprio(1);
    #pragma unroll
    for (int kk = 0; kk < 2; ++kk) {
      bf8v pb[2];
      #pragma unroll
      for (int i = 0; i < 2; ++i)
        pb[i] = *(const bf8v*)&Pt[wave][(i * 16 + l15) * PSTR + kk * 32 + 8 * g];
      #pragma unroll
      for (int n = 0; n < 4; ++n) {
        bf8v vb = frag8(Vb, n * 16 + l15, kk * 4 + g);
        cacc[0][n] = __builtin_amdgcn_mfma_f32_16x16x32_bf16(vb, pb[0], cacc[0][n], 0, 0, 0);
        cacc[1][n] = __builtin_amdgcn_mfma_f32_16x16x32_bf16(vb, pb[1], cacc[1][n], 0, 0, 0);
      }
    }
    __builtin_amdgcn_s_setprio(0);

    __syncthreads();
    cur ^= 1;
  }

  // ---- finalize: cross-group l reduce, normalize, store head-split into Q plane ----
  #pragma unroll
  for (int i = 0; i < 2; ++i) {
    float lf = lpart[i];
    lf += __shfl_xor(lf, 16);
    lf += __shfl_xor(lf, 32);
    float inv = 1.0f / lf;
    int s = q0 + i * 16 + l15;
    #pragma unroll
    for (int n = 0; n < 4; ++n) {
      uint2 w;
      w.x = cvt_pk_bf16(cacc[i][n][0] * inv, cacc[i][n][1] * inv);
      w.y = cvt_pk_bf16(cacc[i][n][2] * inv, cacc[i][n][3] * inv);
      *(uint2*)(CtxQ + base + (size_t)s * DK + n * 16 + g * 4) = w;
    }
  }
}

extern "C" void kernel_launch(void* const* d_in, const int* in_sizes, int n_in,
                              void* d_out, int out_size, void* d_ws, size_t ws_size,
                              hipStream_t stream) {
  const float* x  = (const float*)d_in[0];
  const float* wq = (const float*)d_in[1];
  const float* bq = (const float*)d_in[2];
  const float* wk = (const float*)d_in[3];
  const float* bk = (const float*)d_in[4];
  const float* wv = (const float*)d_in[5];
  const float* bv = (const float*)d_in[6];
  const float* wo = (const float*)d_in[7];
  const float* bo = (const float*)d_in[8];
  float* out = (float*)d_out;

  unsigned short* ws = (unsigned short*)d_ws;
  const size_t WPLANE = (size_t)Dm * Dm;           // 1 Mi elems
  const size_t PLANE  = (size_t)MM * Dm;           // 4 Mi elems
  unsigned short* Wt  = ws;                        // 4 planes: q,k,v,o
  unsigned short* Qh  = ws + PLANE;                // also Ctx (head-split)
  unsigned short* Kh  = ws + 2 * PLANE;
  unsigned short* Vh  = ws + 3 * PLANE;
  unsigned short* Wto = Wt + 3 * WPLANE;

  dim3 blk(256);
  transw_kernel<<<dim3(1024, 4), blk, 0, stream>>>(wq, wk, wv, wo, Wt);
  proj_kernel<<<dim3(Dm / 128, MM / 128, 3), blk, 0, stream>>>(
      x, Wt, bq, bk, bv, Qh, Kh, Vh);
  attn_kernel<<<dim3(SS / 128, BB * NH), blk, 0, stream>>>(Qh, Kh, Vh, Qh);
  outproj_kernel<<<dim3(Dm / 128, MM / 128), blk, 0, stream>>>(Qh, Wto, bo, out);
}

// Round 6
// 151.188 us; speedup vs baseline: 2.3217x; 1.0445x over previous
//
#include <hip/hip_runtime.h>
#include <hip/hip_bf16.h>
#include <math.h>

// MHA forward, all-MFMA path.
//  transw(q,k,v,o) -> proj (x@W, dbuf 2-phase; Q pre-scaled by 1/8*log2e)
//  -> attn (flash, 32x32 swapped QK^T, in-register P via permlane32_swap,
//     8-wave blocks = 4 q-subtiles x 2 key-halves, LDS merge)
//  -> outproj (dbuf 2-phase, head-split A reads).
// ws layout (u16 elems), 32 MiB total:
//  Wt q,k,v,o [0,4M) ; Q [4M,8M) ; K [8M,12M) ; V [12M,16M)
//  Ctx = Q plane (head-split [b,h,s,d]), written by attn after Q-frag hoist.

typedef __attribute__((ext_vector_type(8))) short bf8v;
typedef __attribute__((ext_vector_type(4))) float f32x4;
typedef __attribute__((ext_vector_type(16))) float f32x16;

#define mfma32(a, b, c) __builtin_amdgcn_mfma_f32_32x32x16_bf16((a), (b), (c), 0, 0, 0)

constexpr int Dm = 1024;
constexpr int NH = 16;
constexpr int DK = 64;
constexpr int BB = 2;
constexpr int SS = 2048;
constexpr int MM = BB * SS;   // 4096

__device__ __forceinline__ unsigned short f2bf(float f) {
  union { float f; unsigned u; } v; v.f = f;
  unsigned r = v.u + 0x7fffu + ((v.u >> 16) & 1u);
  return (unsigned short)(r >> 16);
}

__device__ __forceinline__ unsigned cvt_pk_bf16(float lo, float hi) {
  unsigned r;
  asm("v_cvt_pk_bf16_f32 %0, %1, %2" : "=v"(r) : "v"(lo), "v"(hi));
  return r;
}

// vdst[32:63] <-> vsrc[0:31]
__device__ __forceinline__ void swap32(unsigned &a, unsigned &b) {
  asm("v_permlane32_swap_b32 %0, %1" : "+v"(a), "+v"(b));
}

__device__ __forceinline__ void gl_lds16(const void* g, void* l) {
  __builtin_amdgcn_global_load_lds(
      (const __attribute__((address_space(1))) void*)g,
      (__attribute__((address_space(3))) void*)l, 16, 0, 0);
}

// 4-slot swizzle for 64B-row GEMM tiles
__device__ __forceinline__ int swz4(int r) { return (r ^ (r >> 2)) & 3; }
__device__ __forceinline__ bf8v frag4(const unsigned short* base, int R, int s0) {
  return *(const bf8v*)((const char*)base + R * 64 + ((s0 ^ swz4(R)) << 4));
}
// 8-slot swizzled read from 128B-row attn tiles: phys slot = slot ^ (row&7)
__device__ __forceinline__ bf8v rd8(const unsigned short* base, int row, int slot) {
  return *(const bf8v*)((const char*)base + row * 128 + (((slot ^ row) & 7) << 4));
}

// ---------- weight transpose+convert: Wt[o][i] = bf16(W[i][o]) ----------
__global__ __launch_bounds__(256) void transw_kernel(
    const float* __restrict__ w0, const float* __restrict__ w1,
    const float* __restrict__ w2, const float* __restrict__ w3,
    unsigned short* __restrict__ dstBase)
{
  const float* src = (blockIdx.y == 0) ? w0 : (blockIdx.y == 1) ? w1
                   : (blockIdx.y == 2) ? w2 : w3;
  unsigned short* dst = dstBase + (size_t)blockIdx.y * (Dm * Dm);
  int idx = blockIdx.x * 256 + threadIdx.x;
  int i = idx & (Dm - 1);
  int o = (idx >> 10) << 2;
  float4 v = *(const float4*)(src + (size_t)i * Dm + o);
  dst[(size_t)(o + 0) * Dm + i] = f2bf(v.x);
  dst[(size_t)(o + 1) * Dm + i] = f2bf(v.y);
  dst[(size_t)(o + 2) * Dm + i] = f2bf(v.z);
  dst[(size_t)(o + 3) * Dm + i] = f2bf(v.w);
}

// ---------- QKV projection: C = x @ W + b ; Q scaled, Q/K head-split, V transposed ----------
__global__ __launch_bounds__(256) void proj_kernel(
    const float* __restrict__ x, const unsigned short* __restrict__ WtBase,
    const float* __restrict__ bq, const float* __restrict__ bk, const float* __restrict__ bv,
    unsigned short* __restrict__ Qh, unsigned short* __restrict__ Kh,
    unsigned short* __restrict__ Vh)
{
  __shared__ unsigned short As[2][128 * 32];
  __shared__ unsigned short Bs[2][128 * 32];
  const int z = blockIdx.z;
  const unsigned short* W = WtBase + (size_t)z * (Dm * Dm);
  const float* bias = (z == 0) ? bq : (z == 1) ? bk : bv;

  const int tid = threadIdx.x, lane = tid & 63, wave = tid >> 6;
  const int wm = wave >> 1, wn = wave & 1;
  const int m0 = blockIdx.y * 128, n0 = blockIdx.x * 128;
  const int l15 = lane & 15, l4 = lane >> 4;

  const int q1 = tid, q2 = tid + 256;
  const int rw1 = q1 >> 2, sl1 = q1 & 3, c1 = sl1 ^ swz4(rw1);
  const int rw2 = q2 >> 2, sl2 = q2 & 3, c2 = sl2 ^ swz4(rw2);
  const int ldsOff1 = (q1 - lane) * 16, ldsOff2 = (q2 - lane) * 16;

  f32x4 acc[4][4] = {};
  float4 a1, a1b, a2, a2b;

  auto loadA = [&](int k0) {
    const float* s1 = x + (size_t)(m0 + rw1) * Dm + k0 + c1 * 8;
    const float* s2 = x + (size_t)(m0 + rw2) * Dm + k0 + c2 * 8;
    a1 = *(const float4*)s1; a1b = *(const float4*)(s1 + 4);
    a2 = *(const float4*)s2; a2b = *(const float4*)(s2 + 4);
  };
  auto stageB = [&](int buf, int k0) {
    gl_lds16(W + (size_t)(n0 + rw1) * Dm + k0 + c1 * 8, (char*)Bs[buf] + ldsOff1);
    gl_lds16(W + (size_t)(n0 + rw2) * Dm + k0 + c2 * 8, (char*)Bs[buf] + ldsOff2);
  };
  auto writeA = [&](int buf) {
    bf8v v;
    v[0] = (short)f2bf(a1.x);  v[1] = (short)f2bf(a1.y);
    v[2] = (short)f2bf(a1.z);  v[3] = (short)f2bf(a1.w);
    v[4] = (short)f2bf(a1b.x); v[5] = (short)f2bf(a1b.y);
    v[6] = (short)f2bf(a1b.z); v[7] = (short)f2bf(a1b.w);
    *(bf8v*)((char*)As[buf] + rw1 * 64 + (sl1 << 4)) = v;
    v[0] = (short)f2bf(a2.x);  v[1] = (short)f2bf(a2.y);
    v[2] = (short)f2bf(a2.z);  v[3] = (short)f2bf(a2.w);
    v[4] = (short)f2bf(a2b.x); v[5] = (short)f2bf(a2b.y);
    v[6] = (short)f2bf(a2b.z); v[7] = (short)f2bf(a2b.w);
    *(bf8v*)((char*)As[buf] + rw2 * 64 + (sl2 << 4)) = v;
  };

  loadA(0);
  stageB(0, 0);
  writeA(0);
  __syncthreads();

  for (int k0 = 0; k0 < Dm; k0 += 32) {
    const int cur = (k0 >> 5) & 1, nxt = cur ^ 1;
    const bool more = (k0 + 32) < Dm;
    if (more) { loadA(k0 + 32); stageB(nxt, k0 + 32); }

    bf8v af[4], bfr[4];
    #pragma unroll
    for (int i = 0; i < 4; ++i) af[i] = frag4(As[cur], wm * 64 + i * 16 + l15, l4);
    #pragma unroll
    for (int j = 0; j < 4; ++j) bfr[j] = frag4(Bs[cur], wn * 64 + j * 16 + l15, l4);
    __builtin_amdgcn_s_setprio(1);
    #pragma unroll
    for (int i = 0; i < 4; ++i)
      #pragma unroll
      for (int j = 0; j < 4; ++j)
        acc[i][j] = __builtin_amdgcn_mfma_f32_16x16x32_bf16(af[i], bfr[j], acc[i][j], 0, 0, 0);
    __builtin_amdgcn_s_setprio(0);

    if (more) writeA(nxt);
    __syncthreads();
  }

  unsigned short* Out = (z == 0) ? Qh : (z == 1) ? Kh : Vh;
  const float oscale = (z == 0) ? 0.18033688011112042f : 1.0f;  // 1/8 * log2(e)
  #pragma unroll
  for (int i = 0; i < 4; ++i)
    #pragma unroll
    for (int j = 0; j < 4; ++j) {
      int row = m0 + wm * 64 + i * 16 + l4 * 4;
      int col = n0 + wn * 64 + j * 16 + l15;
      float bcol = bias[col];
      int h = col >> 6, d = col & 63;
      #pragma unroll
      for (int r = 0; r < 4; ++r) {
        int rr = row + r;
        int b = rr >> 11, s = rr & 2047;
        unsigned short val = f2bf((acc[i][j][r] + bcol) * oscale);
        if (z < 2)
          Out[(((size_t)(b * NH + h) * SS + s) * DK) + d] = val;
        else
          Out[((size_t)(b * NH + h) * DK + d) * SS + s] = val;   // V transposed
      }
    }
}

// ---------- output projection: out = Ctx @ wo + bo (fp32) ----------
__global__ __launch_bounds__(256) void outproj_kernel(
    const unsigned short* __restrict__ Ctx, const unsigned short* __restrict__ Wto,
    const float* __restrict__ bo, float* __restrict__ Out)
{
  __shared__ unsigned short As[2][128 * 32];
  __shared__ unsigned short Bs[2][128 * 32];
  const int tid = threadIdx.x, lane = tid & 63, wave = tid >> 6;
  const int wm = wave >> 1, wn = wave & 1;
  const int m0 = blockIdx.y * 128, n0 = blockIdx.x * 128;
  const int l15 = lane & 15, l4 = lane >> 4;

  const int q1 = tid, q2 = tid + 256;
  const int rw1 = q1 >> 2, sl1 = q1 & 3, c1 = sl1 ^ swz4(rw1);
  const int rw2 = q2 >> 2, sl2 = q2 & 3, c2 = sl2 ^ swz4(rw2);
  const int ldsOff1 = (q1 - lane) * 16, ldsOff2 = (q2 - lane) * 16;

  auto srcA = [&](int rw, int c, int k0) -> const unsigned short* {
    int rr = m0 + rw, b = rr >> 11, s = rr & 2047;
    int col = k0 + c * 8, h = col >> 6, d = col & 63;
    return Ctx + ((size_t)(b * NH + h) * SS + s) * DK + d;
  };
  auto stageAB = [&](int buf, int k0) {
    gl_lds16(srcA(rw1, c1, k0), (char*)As[buf] + ldsOff1);
    gl_lds16(srcA(rw2, c2, k0), (char*)As[buf] + ldsOff2);
    gl_lds16(Wto + (size_t)(n0 + rw1) * Dm + k0 + c1 * 8, (char*)Bs[buf] + ldsOff1);
    gl_lds16(Wto + (size_t)(n0 + rw2) * Dm + k0 + c2 * 8, (char*)Bs[buf] + ldsOff2);
  };

  f32x4 acc[4][4] = {};

  stageAB(0, 0);
  __syncthreads();

  for (int k0 = 0; k0 < Dm; k0 += 32) {
    const int cur = (k0 >> 5) & 1, nxt = cur ^ 1;
    if (k0 + 32 < Dm) stageAB(nxt, k0 + 32);

    bf8v af[4], bfr[4];
    #pragma unroll
    for (int i = 0; i < 4; ++i) af[i] = frag4(As[cur], wm * 64 + i * 16 + l15, l4);
    #pragma unroll
    for (int j = 0; j < 4; ++j) bfr[j] = frag4(Bs[cur], wn * 64 + j * 16 + l15, l4);
    __builtin_amdgcn_s_setprio(1);
    #pragma unroll
    for (int i = 0; i < 4; ++i)
      #pragma unroll
      for (int j = 0; j < 4; ++j)
        acc[i][j] = __builtin_amdgcn_mfma_f32_16x16x32_bf16(af[i], bfr[j], acc[i][j], 0, 0, 0);
    __builtin_amdgcn_s_setprio(0);
    __syncthreads();
  }

  #pragma unroll
  for (int i = 0; i < 4; ++i)
    #pragma unroll
    for (int j = 0; j < 4; ++j) {
      int row = m0 + wm * 64 + i * 16 + l4 * 4;
      int col = n0 + wn * 64 + j * 16 + l15;
      float bcol = bo[col];
      #pragma unroll
      for (int r = 0; r < 4; ++r)
        Out[(size_t)(row + r) * Dm + col] = acc[i][j][r] + bcol;
    }
}

// ---------- flash attention: 32x32 MFMA, in-register P, intra-block split-K ----------
// Grid: (S/128, B*H), 512 threads = 8 waves = 4 q-subtiles x 2 key-halves.
// Wave (qsub, khalf): 32 q-rows, keys [khalf*1024, +1024) in 16 tiles of 64.
// K/V double-buffered per half (64 KiB). Halves merged via LDS at the end.
__global__ __launch_bounds__(512, 4) void attn_kernel(
    const unsigned short* __restrict__ Q, const unsigned short* __restrict__ K,
    const unsigned short* __restrict__ Vt, unsigned short* __restrict__ CtxQ)
{
  __shared__ __align__(16) unsigned short smem[32768];  // 64 KiB
  unsigned short* KlB = smem;            // [buf][half][64*64]
  unsigned short* VlB = smem + 16384;

  const int tid = threadIdx.x, lane = tid & 63, wave = tid >> 6;
  const int qsub = wave & 3, khalf = wave >> 2;
  const int l31 = lane & 31, hi = lane >> 5;
  const int bh = blockIdx.y;
  const int q0 = blockIdx.x * 128 + qsub * 32;
  const size_t base = (size_t)bh * SS * DK;

  // Q^T B-fragments: lane: q = q0+l31, d = dc*16 + hi*8 + 0..7 (Q pre-scaled)
  bf8v qf[4];
  #pragma unroll
  for (int dc = 0; dc < 4; ++dc)
    qf[dc] = *(const bf8v*)(Q + base + (size_t)(q0 + l31) * DK + dc * 16 + hi * 8);

  float m = -INFINITY, lpart = 0.f;
  f32x16 cacc[2] = {};   // ctx^T d-tiles: rows d = 32n + (reg&3)+8(reg>>2)+4hi, col q=l31

  const int srow = tid >> 3, ssl = tid & 7, sc = ssl ^ (srow & 7);
  const int soff = (tid - lane) * 16;
  auto kslab = [&](int buf, int h) { return KlB + (buf * 2 + h) * 4096; };
  auto vslab = [&](int buf, int h) { return VlB + (buf * 2 + h) * 4096; };
  auto stage = [&](int buf, int kt) {
    gl_lds16(K + base + (size_t)(kt + srow) * DK + sc * 8,          (char*)kslab(buf, 0) + soff);
    gl_lds16(K + base + (size_t)(1024 + kt + srow) * DK + sc * 8,   (char*)kslab(buf, 1) + soff);
    gl_lds16(Vt + base + (size_t)srow * SS + kt + sc * 8,           (char*)vslab(buf, 0) + soff);
    gl_lds16(Vt + base + (size_t)srow * SS + 1024 + kt + sc * 8,    (char*)vslab(buf, 1) + soff);
  };

  constexpr int NT = 16;   // 1024 keys per half / 64
  stage(0, 0);
  __syncthreads();

  for (int t = 0; t < NT; ++t) {
    const int cur = t & 1;
    if (t + 1 < NT) stage(cur ^ 1, (t + 1) * 64);
    const unsigned short* Kb = kslab(cur, khalf);
    const unsigned short* Vb = vslab(cur, khalf);

    // ---- S^T = K @ Q^T : two 32-key tiles ----
    f32x16 st0 = {}, st1 = {};
    __builtin_amdgcn_s_setprio(1);
    #pragma unroll
    for (int dc = 0; dc < 4; ++dc) {
      bf8v kf0 = rd8(Kb, l31, dc * 2 + hi);
      bf8v kf1 = rd8(Kb, 32 + l31, dc * 2 + hi);
      st0 = mfma32(kf0, qf[dc], st0);
      st1 = mfma32(kf1, qf[dc], st1);
    }
    __builtin_amdgcn_s_setprio(0);

    // ---- wave-global max ----
    float mx = -INFINITY;
    #pragma unroll
    for (int r = 0; r < 16; ++r) mx = fmaxf(mx, fmaxf(st0[r], st1[r]));
    mx = fmaxf(mx, __shfl_xor(mx, 1));
    mx = fmaxf(mx, __shfl_xor(mx, 2));
    mx = fmaxf(mx, __shfl_xor(mx, 4));
    mx = fmaxf(mx, __shfl_xor(mx, 8));
    mx = fmaxf(mx, __shfl_xor(mx, 16));
    mx = fmaxf(mx, __shfl_xor(mx, 32));

    // defer-max (THR=8), wave-uniform
    if (mx - m > 8.0f) {
      float alpha = exp2f(m - mx);   // first tile: exp2(-inf) = 0
      m = mx;
      lpart *= alpha;
      #pragma unroll
      for (int n = 0; n < 2; ++n)
        #pragma unroll
        for (int r = 0; r < 16; ++r) cacc[n][r] *= alpha;
    }

    // ---- per 32-key tile: exp, sum, pack (cvt_pk + permlane32_swap), PV ----
    auto process = [&](const f32x16& st, int ktile) {
      float p[16];
      #pragma unroll
      for (int r = 0; r < 16; ++r) p[r] = exp2f(st[r] - m);
      float sA = ((p[0] + p[1]) + (p[2] + p[3])) + ((p[4] + p[5]) + (p[6] + p[7]));
      float sB = ((p[8] + p[9]) + (p[10] + p[11])) + ((p[12] + p[13]) + (p[14] + p[15]));
      lpart += sA + sB;
      #pragma unroll
      for (int c = 0; c < 2; ++c) {
        const int o = c * 8;
        unsigned A  = cvt_pk_bf16(p[o + 0], p[o + 1]);
        unsigned B  = cvt_pk_bf16(p[o + 4], p[o + 5]);
        unsigned Cw = cvt_pk_bf16(p[o + 2], p[o + 3]);
        unsigned Dw = cvt_pk_bf16(p[o + 6], p[o + 7]);
        swap32(A, B); swap32(Cw, Dw);
        union { bf8v v; unsigned w[4]; } pf;
        pf.w[0] = A; pf.w[1] = Cw; pf.w[2] = B; pf.w[3] = Dw;
        const int slot = ktile * 4 + c * 2 + hi;
        bf8v vb0 = rd8(Vb, l31, slot);
        bf8v vb1 = rd8(Vb, 32 + l31, slot);
        __builtin_amdgcn_s_setprio(1);
        cacc[0] = mfma32(vb0, pf.v, cacc[0]);
        cacc[1] = mfma32(vb1, pf.v, cacc[1]);
        __builtin_amdgcn_s_setprio(0);
      }
    };
    process(st0, 0);
    process(st1, 1);

    __syncthreads();
  }

  // ---- merge the two key-halves via LDS, normalize, store ----
  float lf = lpart + __shfl_xor(lpart, 32);   // per-q row sum (dup across halves)
  float* scr = (float*)smem;                  // 64 KiB >= 4 * 2176 * 4B
  float* fs = scr + qsub * 2176;

  if (khalf == 1) {
    #pragma unroll
    for (int n = 0; n < 2; ++n)
      #pragma unroll
      for (int r = 0; r < 16; ++r)
        fs[(n * 16 + r) * 64 + lane] = cacc[n][r];
    fs[2048 + lane] = lf;
    if (lane == 0) fs[2048 + 64] = m;
  }
  __syncthreads();
  if (khalf == 0) {
    float mB = fs[2048 + 64];
    float lB = fs[2048 + lane];
    float mt = fmaxf(m, mB);
    float a  = exp2f(m - mt), b2 = exp2f(mB - mt);
    float inv = 1.0f / (lf * a + lB * b2);
    float fa = a * inv, fb = b2 * inv;
    #pragma unroll
    for (int n = 0; n < 2; ++n)
      #pragma unroll
      for (int j = 0; j < 4; ++j) {
        float v0 = cacc[n][4 * j + 0] * fa + fs[(n * 16 + 4 * j + 0) * 64 + lane] * fb;
        float v1 = cacc[n][4 * j + 1] * fa + fs[(n * 16 + 4 * j + 1) * 64 + lane] * fb;
        float v2 = cacc[n][4 * j + 2] * fa + fs[(n * 16 + 4 * j + 2) * 64 + lane] * fb;
        float v3 = cacc[n][4 * j + 3] * fa + fs[(n * 16 + 4 * j + 3) * 64 + lane] * fb;
        uint2 w;
        w.x = cvt_pk_bf16(v0, v1);
        w.y = cvt_pk_bf16(v2, v3);
        int d = n * 32 + 8 * j + 4 * hi;
        *(uint2*)(CtxQ + base + (size_t)(q0 + l31) * DK + d) = w;
      }
  }
}

extern "C" void kernel_launch(void* const* d_in, const int* in_sizes, int n_in,
                              void* d_out, int out_size, void* d_ws, size_t ws_size,
                              hipStream_t stream) {
  const float* x  = (const float*)d_in[0];
  const float* wq = (const float*)d_in[1];
  const float* bq = (const float*)d_in[2];
  const float* wk = (const float*)d_in[3];
  const float* bk = (const float*)d_in[4];
  const float* wv = (const float*)d_in[5];
  const float* bv = (const float*)d_in[6];
  const float* wo = (const float*)d_in[7];
  const float* bo = (const float*)d_in[8];
  float* out = (float*)d_out;

  unsigned short* ws = (unsigned short*)d_ws;
  const size_t WPLANE = (size_t)Dm * Dm;           // 1 Mi elems
  const size_t PLANE  = (size_t)MM * Dm;           // 4 Mi elems
  unsigned short* Wt  = ws;                        // 4 planes: q,k,v,o
  unsigned short* Qh  = ws + PLANE;                // also Ctx (head-split)
  unsigned short* Kh  = ws + 2 * PLANE;
  unsigned short* Vh  = ws + 3 * PLANE;
  unsigned short* Wto = Wt + 3 * WPLANE;

  transw_kernel<<<dim3(1024, 4), dim3(256), 0, stream>>>(wq, wk, wv, wo, Wt);
  proj_kernel<<<dim3(Dm / 128, MM / 128, 3), dim3(256), 0, stream>>>(
      x, Wt, bq, bk, bv, Qh, Kh, Vh);
  attn_kernel<<<dim3(SS / 128, BB * NH), dim3(512), 0, stream>>>(Qh, Kh, Vh, Qh);
  outproj_kernel<<<dim3(Dm / 128, MM / 128), dim3(256), 0, stream>>>(Qh, Wto, bo, out);
}